// Round 1
// baseline (453.508 us; speedup 1.0000x reference)
//
#include <hip/hip_runtime.h>
#include <hip/hip_bf16.h>

#define BH 32      // bs*h
#define L  1024    // qlen == slen
#define D  64      // head dim
#define QT 16      // q rows per block
#define WROW 264   // staged-weights LDS row stride in bf16 (528 B: 16B-aligned; <=2-way banks)

typedef __bf16 bf16x8 __attribute__((ext_vector_type(8)));
typedef __bf16 bf16x4 __attribute__((ext_vector_type(4)));
typedef float  f32x4  __attribute__((ext_vector_type(4)));

// ---------------------------------------------------------------------------
// Prep: k [bh][d][s] -> ktb [bh][s][d] bf16 (blocks 0..255);
//       v [bh][s][d] -> vtb [bh][d][s] bf16 (blocks 256..511).
// q conversion now happens inside attn_kernel (each block owns its tile).
// ---------------------------------------------------------------------------
__global__ __launch_bounds__(256) void prep_kernel(
    const float* __restrict__ k, const float* __restrict__ v,
    __bf16* __restrict__ ktb, __bf16* __restrict__ vtb)
{
  __shared__ __align__(16) __bf16 T[128 * 66];  // k view [128s][66]; v view [64d][130s]
  const int tid = threadIdx.x;
  const int b = blockIdx.x;

  if (b < 256) {
    // k transpose: [d][s] -> [s][d], 128-s chunk per block
    const int bh = b >> 3, chunk = b & 7;
    const int s0 = chunk << 7;
    const float* kin = k + (size_t)bh * D * L;
    #pragma unroll
    for (int i = 0; i < 32; ++i) {          // coalesced reads along s
      const int e = i * 256 + tid;
      const int d = e >> 7, s = e & 127;
      T[s * 66 + d] = (__bf16)kin[(size_t)d * L + s0 + s];
    }
    __syncthreads();
    unsigned int* outw = (unsigned int*)ktb;
    const size_t obase = ((size_t)bh * L * D + (size_t)s0 * D) >> 1;  // dword idx
    #pragma unroll
    for (int i = 0; i < 16; ++i) {          // fully coalesced contiguous writes
      const int e = i * 256 + tid;
      const int s = e >> 5, dp = e & 31;
      outw[obase + e] = *(const unsigned int*)&T[s * 66 + dp * 2];
    }
  } else {
    // v transpose: [s][d] -> [d][s], 128-s chunk per block
    const int bb = b - 256;
    const int bh = bb >> 3, chunk = bb & 7;
    const int s0 = chunk << 7;
    const float* vin = v + (size_t)bh * L * D + (size_t)s0 * D;
    #pragma unroll
    for (int i = 0; i < 32; ++i) {          // coalesced reads
      const int e = i * 256 + tid;
      const int s = e >> 6, d = e & 63;
      T[d * 130 + s] = (__bf16)vin[e];
    }
    __syncthreads();
    unsigned int* outw = (unsigned int*)vtb;
    #pragma unroll
    for (int i = 0; i < 16; ++i) {
      const int e = i * 256 + tid;
      const int d = e >> 6, sp = e & 63;
      outw[(size_t)bh * (L * D / 2) + (size_t)d * (L / 2) + (s0 >> 1) + sp] =
          *(const unsigned int*)&T[d * 130 + sp * 2];
    }
  }
}

// ---------------------------------------------------------------------------
// Main fused kernel. Key change vs prior version: MFMA operands are SWAPPED
// (A = k-fragment, B = q-fragment) so the C fragment is S^T-shaped:
//   lane(quad,l16), reg j  ->  S[qrow = l16][s = n0 + quad*4 + j]
// i.e. each lane owns 4 CONSECUTIVE s of ONE q-row. This makes prev loads and
// out_s/out_w stores dwordx4 (each instr covers 16 dense 64B lines), collapses
// the row reduction to in-lane + 2 shuffles, and makes rm/rs scalars.
// ---------------------------------------------------------------------------
__global__ __launch_bounds__(256, 4) void attn_kernel(
    const float* __restrict__ q, const __bf16* __restrict__ ktb,
    const __bf16* __restrict__ vtb,
    const float* __restrict__ prev, const float* __restrict__ scale_p,
    float* __restrict__ out_o, float* __restrict__ out_w,
    float* __restrict__ out_s)
{
  // Per-wave staged weights [16 rows][WROW] bf16; aliased with the 16 KB
  // cross-wave O reduction buffer (separated by __syncthreads).
  __shared__ __align__(16) char smem[4 * 16 * WROW * 2];  // 33792 B
  __shared__ float red_m[4][16];
  __shared__ float red_s[4][16];
  __bf16* w_stage = (__bf16*)smem;
  float*  o_red   = (float*)smem;

  const int tid  = threadIdx.x;
  const int wv   = tid >> 6;
  const int lane = tid & 63;
  const int quad = lane >> 4;
  const int l16  = lane & 15;

  // XCD-affinity swizzle: blocks dispatch round-robin over 8 XCDs; map so
  // XCD r owns bh in {4r..4r+3} entirely -> each bh's 256 KB ktb/vtb stays
  // resident in ONE XCD's L2 (fetched from L3 once instead of 8x).
  const int swz = (blockIdx.x & 7) * 256 + (blockIdx.x >> 3);
  const int bh  = swz >> 6;
  const int qt  = swz & 63;
  const float scale = scale_p[0];

  // A fragments (q tile rows): read fp32 directly, convert in-reg
  const float* qr0 = q + ((size_t)bh * L + qt * QT + l16) * D + quad * 8;
  const float4 f0 = *(const float4*)(qr0);
  const float4 f1 = *(const float4*)(qr0 + 4);
  const float4 f2 = *(const float4*)(qr0 + 32);
  const float4 f3 = *(const float4*)(qr0 + 36);
  bf16x8 a0, a1;
  a0[0] = (__bf16)f0.x; a0[1] = (__bf16)f0.y; a0[2] = (__bf16)f0.z; a0[3] = (__bf16)f0.w;
  a0[4] = (__bf16)f1.x; a0[5] = (__bf16)f1.y; a0[6] = (__bf16)f1.z; a0[7] = (__bf16)f1.w;
  a1[0] = (__bf16)f2.x; a1[1] = (__bf16)f2.y; a1[2] = (__bf16)f2.z; a1[3] = (__bf16)f2.w;
  a1[4] = (__bf16)f3.x; a1[5] = (__bf16)f3.y; a1[6] = (__bf16)f3.z; a1[7] = (__bf16)f3.w;

  const __bf16* kt_bh = ktb + (size_t)bh * L * D;
  const size_t row_base = (size_t)bh * L * L + (size_t)(qt * QT) * L;
  const int nbase = wv << 8;  // this wave's 256-wide s-chunk base

  // ---- phase 1a: issue ALL prev loads, vectorized (16 x dwordx4 in flight) ----
  f32x4 p[16];
  const float* prow = prev + row_base + (size_t)l16 * L + nbase + quad * 4;
  #pragma unroll
  for (int nt = 0; nt < 16; ++nt)
    p[nt] = __builtin_nontemporal_load((const f32x4*)(prow + nt * 16));
  __builtin_amdgcn_sched_barrier(0);  // don't sink the loads into the MFMA loop

  // ---- phase 1b: S^T-fragment MFMA; scores out as dwordx4; keep in regs ----
  #pragma unroll
  for (int nt = 0; nt < 16; ++nt) {
    const int n0 = nbase + nt * 16;
    const __bf16* krow = kt_bh + (size_t)(n0 + l16) * D + quad * 8;
    const bf16x8 b0 = *(const bf16x8*)(krow);
    const bf16x8 b1 = *(const bf16x8*)(krow + 32);
    f32x4 c = {0.f, 0.f, 0.f, 0.f};
    c = __builtin_amdgcn_mfma_f32_16x16x32_bf16(b0, a0, c, 0, 0, 0);  // swapped!
    c = __builtin_amdgcn_mfma_f32_16x16x32_bf16(b1, a1, c, 0, 0, 0);
    f32x4 sc;
    #pragma unroll
    for (int j = 0; j < 4; ++j) sc[j] = c[j] * scale + p[nt][j];
    __builtin_nontemporal_store(
        sc, (f32x4*)(out_s + row_base + (size_t)l16 * L + n0 + quad * 4));
    p[nt] = sc;
  }

  // ---- phase 2: row softmax over full s=1024 (row == l16, scalar m/s) ----
  float mj[4];
  #pragma unroll
  for (int j = 0; j < 4; ++j) {
    float m = p[0][j];
    #pragma unroll
    for (int nt = 1; nt < 16; ++nt) m = fmaxf(m, p[nt][j]);
    mj[j] = m;
  }
  float m = fmaxf(fmaxf(mj[0], mj[1]), fmaxf(mj[2], mj[3]));
  m = fmaxf(m, __shfl_xor(m, 16, 64));   // reduce across quads (same l16)
  m = fmaxf(m, __shfl_xor(m, 32, 64));
  if (lane < 16) red_m[wv][l16] = m;
  __syncthreads();
  m = fmaxf(fmaxf(red_m[0][l16], red_m[1][l16]),
            fmaxf(red_m[2][l16], red_m[3][l16]));

  float sj[4] = {0.f, 0.f, 0.f, 0.f};
  #pragma unroll
  for (int nt = 0; nt < 16; ++nt) {
    #pragma unroll
    for (int j = 0; j < 4; ++j) {
      const float e = __expf(p[nt][j] - m);
      p[nt][j] = e;
      sj[j] += e;
    }
  }
  float s = (sj[0] + sj[1]) + (sj[2] + sj[3]);
  s += __shfl_xor(s, 16, 64);
  s += __shfl_xor(s, 32, 64);
  if (lane < 16) red_s[wv][l16] = s;
  __syncthreads();
  const float inv =
      1.0f / (red_s[0][l16] + red_s[1][l16] + red_s[2][l16] + red_s[3][l16]);

  // ---- weights: dwordx4 fp32 out + b64 bf16 LDS stage (wave-private) ----
  __bf16* wl = w_stage + wv * (16 * WROW);
  #pragma unroll
  for (int nt = 0; nt < 16; ++nt) {
    f32x4 wt;
    bf16x4 wb;
    #pragma unroll
    for (int j = 0; j < 4; ++j) {
      wt[j] = p[nt][j] * inv;
      wb[j] = (__bf16)wt[j];
    }
    __builtin_nontemporal_store(
        wt, (f32x4*)(out_w + row_base + (size_t)l16 * L + nbase + nt * 16 + quad * 4));
    *(bf16x4*)(wl + l16 * WROW + nt * 16 + quad * 4) = wb;
  }
  // wave-private LDS region: no block barrier needed before own-wave reads

  // ---- phase 3: O_partial = P_chunk @ V_chunk via MFMA ----
  const __bf16* vt_bh = vtb + (size_t)bh * D * L;
  f32x4 o[4];
  #pragma unroll
  for (int nt = 0; nt < 4; ++nt) o[nt] = (f32x4){0.f, 0.f, 0.f, 0.f};
  #pragma unroll
  for (int ks = 0; ks < 8; ++ks) {
    const bf16x8 aw = *(const bf16x8*)(wl + l16 * WROW + ks * 32 + quad * 8);
    #pragma unroll
    for (int nt = 0; nt < 4; ++nt) {
      const __bf16* vrow =
          vt_bh + (size_t)(nt * 16 + l16) * L + (nbase + ks * 32 + quad * 8);
      const bf16x8 bv = *(const bf16x8*)vrow;
      o[nt] = __builtin_amdgcn_mfma_f32_16x16x32_bf16(aw, bv, o[nt], 0, 0, 0);
    }
  }

  // ---- cross-wave O reduction (o_red aliases w_stage) ----
  __syncthreads();  // everyone done reading w_stage
  #pragma unroll
  for (int nt = 0; nt < 4; ++nt) {
    #pragma unroll
    for (int j = 0; j < 4; ++j)
      o_red[wv * 1024 + (quad * 4 + j) * 64 + nt * 16 + l16] = o[nt][j];
  }
  __syncthreads();
  const size_t obase = (size_t)bh * L * D + (size_t)(qt * QT) * D;
  #pragma unroll
  for (int i = 0; i < 4; ++i) {
    const int idx = i * 256 + tid;
    const float sum =
        o_red[idx] + o_red[1024 + idx] + o_red[2048 + idx] + o_red[3072 + idx];
    out_o[obase + idx] = sum;
  }
}

// ---------------------------------------------------------------------------
extern "C" void kernel_launch(void* const* d_in, const int* in_sizes, int n_in,
                              void* d_out, int out_size, void* d_ws,
                              size_t ws_size, hipStream_t stream)
{
  const float* q     = (const float*)d_in[0];
  const float* k     = (const float*)d_in[1];
  const float* v     = (const float*)d_in[2];
  const float* prev  = (const float*)d_in[3];
  const float* scale = (const float*)d_in[4];

  float* out_o = (float*)d_out;                  // [32][1024][64]
  float* out_w = out_o + (size_t)BH * L * D;     // [32][1024][1024]
  float* out_s = out_w + (size_t)BH * L * L;     // [32][1024][1024]

  __bf16* ktb = (__bf16*)d_ws;                   // 4 MB ([bh][s][d])
  __bf16* vtb = ktb + (size_t)BH * L * D;        // 4 MB ([bh][d][s])

  prep_kernel<<<512, 256, 0, stream>>>(k, v, ktb, vtb);
  attn_kernel<<<2048, 256, 0, stream>>>(q, ktb, vtb, prev, scale,
                                        out_o, out_w, out_s);
}